// Round 4
// baseline (216.755 us; speedup 1.0000x reference)
//
#include <hip/hip_runtime.h>

#define NCLS 14
#define BATCH 2
#define NUM_BINS (BATCH * NCLS)

// d_ws layout: float sums[NUM_BINS] | int counts[NUM_BINS]

__global__ void zero_bins_kernel(float* __restrict__ sums, int* __restrict__ counts) {
    int i = threadIdx.x;
    if (i < NUM_BINS) { sums[i] = 0.0f; counts[i] = 0; }
}

__global__ __launch_bounds__(256) void kl_kernel(
        const float* __restrict__ S, const float* __restrict__ T,
        const int* __restrict__ gt,
        float* __restrict__ gsums, int* __restrict__ gcnts,
        int N /* voxels per batch image */) {
    __shared__ float lsum[NUM_BINS];
    __shared__ int lcnt[NUM_BINS];
    if (threadIdx.x < NUM_BINS) { lsum[threadIdx.x] = 0.0f; lcnt[threadIdx.x] = 0; }
    __syncthreads();

    const int v0 = blockIdx.x * blockDim.x + threadIdx.x;  // one voxel per thread
    const int b = (v0 >= N) ? 1 : 0;                       // BATCH == 2
    const int n = v0 - b * N;

    const float* Sb = S + (size_t)b * NCLS * N + n;
    const float* Tb = T + (size_t)b * NCLS * N + n;

    // ---- 28 independent scalar loads, all destinations live (28 VGPRs) ----
    // Interleaved S/T order so consumption order (c ascending) matches
    // cascading vmcnt waits: while computing c, loads c+1..13 stay in flight.
    float s[NCLS], t[NCLS];
#pragma unroll
    for (int c = 0; c < NCLS; ++c) {
        s[c] = Sb[(size_t)c * N];
        t[c] = Tb[(size_t)c * N];
    }
    const int g = gt[v0];

    float Zs = 0.f, Zt = 0.f, At = 0.f, As = 0.f;
#pragma unroll
    for (int c = 0; c < NCLS; ++c) {
        float et = __expf(t[c]);
        Zt += et;
        At = fmaf(et, t[c], At);
        As = fmaf(et, s[c], As);
        Zs += __expf(s[c]);
    }
    // kl = sum_c q(logq - logp) = (At - As)/Zt - log(Zt) + log(Zs)
    float kl = (At - As) / Zt - __logf(Zt) + __logf(Zs);

    int c = min(max(g, 0), NCLS - 1);
    atomicAdd(&lsum[b * NCLS + c], kl);
    atomicAdd(&lcnt[b * NCLS + c], 1);

    __syncthreads();
    if (threadIdx.x < NUM_BINS) {
        atomicAdd(&gsums[threadIdx.x], lsum[threadIdx.x]);
        atomicAdd(&gcnts[threadIdx.x], lcnt[threadIdx.x]);
    }
}

__global__ void finalize_kernel(const float* __restrict__ sums,
                                const int* __restrict__ counts,
                                float* __restrict__ out) {
    if (threadIdx.x == 0) {
        float loss = 0.0f;
        for (int b = 0; b < BATCH; ++b) {
            for (int cls = 1; cls < NCLS; ++cls) {   // class 0 (background) excluded
                int idx = b * NCLS + cls;
                int cnt = counts[idx];
                if (cnt > 0) loss += sums[idx] / ((float)NCLS * (float)cnt);
            }
        }
        out[0] = loss;  // TAU^2 = 1, LOSS_WEIGHT = 1
    }
}

extern "C" void kernel_launch(void* const* d_in, const int* in_sizes, int n_in,
                              void* d_out, int out_size, void* d_ws, size_t ws_size,
                              hipStream_t stream) {
    const float* S = (const float*)d_in[0];
    const float* T = (const float*)d_in[1];
    const int* gt = (const int*)d_in[2];
    float* out = (float*)d_out;

    float* sums = (float*)d_ws;
    int* cnts = (int*)((char*)d_ws + NUM_BINS * sizeof(float));

    const int totalVox = in_sizes[2];       // B * 96^3 = 1,769,472 = 6912 * 256
    const int N = totalVox / BATCH;         // 884,736

    const int block = 256;
    const int grid = totalVox / block;      // 6912, exact

    zero_bins_kernel<<<1, 64, 0, stream>>>(sums, cnts);
    kl_kernel<<<grid, block, 0, stream>>>(S, T, gt, sums, cnts, N);
    finalize_kernel<<<1, 64, 0, stream>>>(sums, cnts, out);
}